// Round 1
// baseline (31.671 us; speedup 1.0000x reference)
//
#include <hip/hip_runtime.h>

// LSTM encoder with EOS freeze. Key facts:
//  - h0 = c0 = 0, so step 0 needs only x0 @ Wx + b  (h@Wh term is exactly 0).
//  - is_eos[b] |= (embedding[token][1] != 0): a float from N(0,0.02) -> true
//    after the first step with probability 1, freezing state at step-0 values.
//  - Kernel A computes step 0 fully parallel and the eos flags.
//  - Kernel B runs the remaining steps 1..511 per-batch (one block per batch)
//    with a faithful early-exit; for the bench input it exits immediately.

#define SEQ 512
#define EDIM 512
#define HDIM 512
#define BATCH 64

__device__ __forceinline__ float sigf(float x) { return 1.0f / (1.0f + __expf(-x)); }

// ---- Kernel A: step 0 (no recurrence), writes c,h to d_out and eos flags to ws.
// Grid: 256 blocks = 8 batch-groups (8 batches each) x 32 j-chunks (16 hidden units each).
// Block owns all 4 gate columns for its 16 j's -> pointwise update is block-local.
__global__ __launch_bounds__(512) void step0_kernel(
    const int* __restrict__ inputs, const float* __restrict__ emb,
    const float* __restrict__ Wx, const float* __restrict__ bias,
    float* __restrict__ out, int* __restrict__ eos_ws)
{
    const int jchunk = blockIdx.x >> 3;   // 0..31
    const int bb     = blockIdx.x & 7;    // 0..7
    const int b0     = bb * 8;
    const int j0     = jchunk * 16;
    const int t      = threadIdx.x;       // 512 threads

    __shared__ float x_s[8][EDIM];        // 8 staged embedding rows (16 KB)
    __shared__ float g_s[8][64];          // gates for 8 batches x (4 gates x 16 j)

    // Stage x0 rows: wave r handles batch b0+r (t>>6 = wave id), coalesced.
    {
        const int r    = t >> 6;
        const int lane = t & 63;
        const int tok  = inputs[(b0 + r) * SEQ];            // inputs[b][0]
        const float* src = emb + (size_t)tok * EDIM;
        #pragma unroll
        for (int k = 0; k < 8; ++k)
            x_s[r][lane + k * 64] = src[lane + k * 64];
    }
    __syncthreads();

    // One dot product per thread: gates[b0+blocal][col], col = gate*512 + j0 + jj.
    const int colLocal = t & 63;          // lanes -> 64 cols (coalesced-ish, 4x64B runs)
    const int blocal   = t >> 6;          // wave-uniform -> x_s broadcast reads
    const int gate     = colLocal >> 4;
    const int jj       = colLocal & 15;
    const int col      = gate * 512 + j0 + jj;

    float acc = bias[col];
    const float* xrow = x_s[blocal];
    #pragma unroll 8
    for (int e = 0; e < EDIM; ++e)
        acc += xrow[e] * Wx[(size_t)e * 2048 + col];

    g_s[blocal][colLocal] = acc;
    __syncthreads();

    // Pointwise LSTM update with c0 = 0:  c = sig(i)*tanh(g),  h = sig(o)*tanh(c).
    if (t < 128) {
        const int bl = t >> 4;
        const int j  = t & 15;
        float iv = sigf(g_s[bl][0 * 16 + j]);
        float gg = tanhf(g_s[bl][2 * 16 + j]);
        float ov = sigf(g_s[bl][3 * 16 + j]);
        float c  = iv * gg;
        float h  = ov * tanhf(c);
        const int b = b0 + bl;
        out[b * HDIM + j0 + j]               = c;
        out[BATCH * HDIM + b * HDIM + j0 + j] = h;
    }

    // EOS flags after step 0: is_eos[b] = (emb[tok0][EOS_ID=1] != 0).
    if (jchunk == 0 && t < 8) {
        const int b   = b0 + t;
        const int tok = inputs[b * SEQ];
        eos_ws[b] = (emb[(size_t)tok * EDIM + 1] != 0.0f) ? 1 : 0;
    }
}

// ---- Kernel B: faithful sequential tail, steps 1..511. One block per batch.
// Exits immediately if the batch froze at step 0 (true for the bench input).
__global__ __launch_bounds__(512) void tail_kernel(
    const int* __restrict__ inputs, const float* __restrict__ emb,
    const float* __restrict__ Wx, const float* __restrict__ Wh,
    const float* __restrict__ bias, float* __restrict__ out,
    const int* __restrict__ eos_ws)
{
    const int b = blockIdx.x;
    if (eos_ws[b]) return;                 // state already final in d_out

    const int t = threadIdx.x;             // 512 threads, one hidden unit each
    __shared__ float h_s[HDIM];
    __shared__ float c_s[HDIM];
    __shared__ float x_s[EDIM];

    c_s[t] = out[b * HDIM + t];
    h_s[t] = out[BATCH * HDIM + b * HDIM + t];
    bool eos = false;
    __syncthreads();

    for (int s = 1; s < SEQ; ++s) {
        const int tok = inputs[b * SEQ + s];
        x_s[t] = emb[(size_t)tok * EDIM + t];
        __syncthreads();                   // x_s visible; prev h_s writes visible

        float g0 = bias[t];                // i
        float g1 = bias[512 + t];          // f
        float g2 = bias[1024 + t];         // g
        float g3 = bias[1536 + t];         // o
        for (int e = 0; e < EDIM; ++e) {
            const float xv = x_s[e];
            const float hv = h_s[e];
            const float* wxr = Wx + (size_t)e * 2048;
            const float* whr = Wh + (size_t)e * 2048;
            g0 += xv * wxr[t]        + hv * whr[t];
            g1 += xv * wxr[512 + t]  + hv * whr[512 + t];
            g2 += xv * wxr[1024 + t] + hv * whr[1024 + t];
            g3 += xv * wxr[1536 + t] + hv * whr[1536 + t];
        }
        const float nc = sigf(g1) * c_s[t] + sigf(g0) * tanhf(g2);
        const float nh = sigf(g3) * tanhf(nc);
        eos = eos || (x_s[1] != 0.0f);     // token s raises the flag AFTER this update
        __syncthreads();                   // all reads of h_s/x_s done
        c_s[t] = nc;
        h_s[t] = nh;
        __syncthreads();                   // new state visible
        if (eos) break;                    // uniform across the block
    }

    out[b * HDIM + t]                 = c_s[t];
    out[BATCH * HDIM + b * HDIM + t]  = h_s[t];
}

extern "C" void kernel_launch(void* const* d_in, const int* in_sizes, int n_in,
                              void* d_out, int out_size, void* d_ws, size_t ws_size,
                              hipStream_t stream) {
    const int*   inputs = (const int*)  d_in[0];
    const float* emb    = (const float*)d_in[1];
    const float* Wx     = (const float*)d_in[2];
    const float* Wh     = (const float*)d_in[3];
    const float* bias   = (const float*)d_in[4];
    float* out   = (float*)d_out;
    int*   eosws = (int*)d_ws;

    step0_kernel<<<256, 512, 0, stream>>>(inputs, emb, Wx, bias, out, eosws);
    tail_kernel<<<BATCH, 512, 0, stream>>>(inputs, emb, Wx, Wh, bias, out, eosws);
}

// Round 2
// 15.224 us; speedup vs baseline: 2.0803x; 2.0803x over previous
//
#include <hip/hip_runtime.h>

// Masked LSTM encoder. Facts exploited:
//  - h0 = c0 = 0  ->  step 0 is gates = x0 @ Wx + b only; f-gate is dead (c0=0).
//  - is_eos[b] |= (embedding[token][EOS_ID=1] != 0): a N(0,0.02) float -> true
//    after step 0 with probability 1, freezing (c,h) at step-0 values.
//  - K1: split-K GEMM partials for x0@Wx (lane=batch, wave-uniform Wx cols ->
//    scalar loads; Wx element fetched once globally).
//  - K2: reduce partials + bias + pointwise LSTM + eos flags.
//  - K3: faithful sequential tail for non-frozen batches (no-op on this input).

#define SEQ   512
#define EDIM  512
#define HDIM  512
#define BATCH 64

#define ECHUNKS 8           // split-K factor
#define ELEN    (EDIM / ECHUNKS)   // 64 e's per chunk
#define CTILES  32          // 2048 cols / 64
#define WS_PARTIAL_OFF 4096 // bytes; eos flags live at ws[0..63] (int)

__device__ __forceinline__ float sigf(float x) { return 1.0f / (1.0f + __expf(-x)); }

// ---- K1: partial GEMM. Block = 64-col tile x 64-e chunk, 512 threads.
// lane (t&63) = batch, wave (t>>6) = 8 consecutive cols (wave-uniform -> s_load).
__global__ __launch_bounds__(512) void gemm_partial_kernel(
    const int* __restrict__ inputs, const float* __restrict__ emb,
    const float* __restrict__ Wx, float* __restrict__ partials)
{
    const int ct = blockIdx.x >> 3;         // 0..31
    const int ec = blockIdx.x & 7;          // 0..7
    const int e0 = ec * ELEN;
    const int t  = threadIdx.x;
    const int lane = t & 63;                // = batch
    const int w    = __builtin_amdgcn_readfirstlane(t >> 6);  // wave id 0..7
    const int cbase = ct * 64 + w * 8;      // wave-uniform col base

    __shared__ float x_s[BATCH][ELEN + 1];  // +1 pad -> 2 lanes/bank (free)

    // Stage x0 rows: wave w stages batches w*8..w*8+7, lanes over e (coalesced).
    #pragma unroll
    for (int k = 0; k < 8; ++k) {
        const int b   = w * 8 + k;
        const int tok = inputs[b * SEQ];
        x_s[b][lane] = emb[(size_t)tok * EDIM + e0 + lane];
    }
    __syncthreads();

    float acc[8];
    #pragma unroll
    for (int wc = 0; wc < 8; ++wc) acc[wc] = 0.0f;

    #pragma unroll 4
    for (int e = 0; e < ELEN; ++e) {
        const float xv = x_s[lane][e];                       // per-lane (batch) x
        const float* row = Wx + (size_t)(e0 + e) * 2048 + cbase;  // wave-uniform
        #pragma unroll
        for (int wc = 0; wc < 8; ++wc)
            acc[wc] += xv * row[wc];                         // scalar-loadable Wx
    }

    // partials[ec][col][b] — lanes consecutive -> coalesced 256B stores.
    float* pb = partials + ((size_t)ec * 2048 + cbase) * BATCH + lane;
    #pragma unroll
    for (int wc = 0; wc < 8; ++wc)
        pb[(size_t)wc * BATCH] = acc[wc];
}

// ---- K2: reduce ECHUNKS partials + bias, pointwise LSTM (c0=0), eos flags.
// g = blockIdx*256+t; b = g&63 (lane), j = g>>6 (wave-uniform) -> coalesced loads.
__global__ __launch_bounds__(256) void reduce_pointwise_kernel(
    const int* __restrict__ inputs, const float* __restrict__ emb,
    const float* __restrict__ partials, const float* __restrict__ bias,
    float* __restrict__ out, int* __restrict__ eos_flags)
{
    const int g = blockIdx.x * 256 + threadIdx.x;
    const int b = g & 63;
    const int j = g >> 6;                    // 0..511

    float gi = bias[j];
    float gg = bias[1024 + j];
    float go = bias[1536 + j];
    #pragma unroll
    for (int ec = 0; ec < ECHUNKS; ++ec) {
        const float* p = partials + (size_t)ec * 2048 * BATCH + b;
        gi += p[(size_t)(j)          * BATCH];
        gg += p[(size_t)(1024 + j)   * BATCH];
        go += p[(size_t)(1536 + j)   * BATCH];
    }

    const float c = sigf(gi) * tanhf(gg);    // c0 = 0 -> f-gate dead
    const float h = sigf(go) * tanhf(c);
    out[b * HDIM + j]                  = c;
    out[BATCH * HDIM + b * HDIM + j]   = h;

    // EOS flags after step 0.
    if (blockIdx.x == 0 && threadIdx.x < BATCH) {
        const int bb  = threadIdx.x;
        const int tok = inputs[bb * SEQ];
        eos_flags[bb] = (emb[(size_t)tok * EDIM + 1] != 0.0f) ? 1 : 0;
    }
}

// ---- K3: faithful sequential tail, steps 1..511. One block per batch.
__global__ __launch_bounds__(512) void tail_kernel(
    const int* __restrict__ inputs, const float* __restrict__ emb,
    const float* __restrict__ Wx, const float* __restrict__ Wh,
    const float* __restrict__ bias, float* __restrict__ out,
    const int* __restrict__ eos_flags)
{
    const int b = blockIdx.x;
    if (eos_flags[b]) return;                // state already final in d_out

    const int t = threadIdx.x;               // 512 threads, one hidden unit each
    __shared__ float h_s[HDIM];
    __shared__ float c_s[HDIM];
    __shared__ float x_s[EDIM];

    c_s[t] = out[b * HDIM + t];
    h_s[t] = out[BATCH * HDIM + b * HDIM + t];
    bool eos = false;
    __syncthreads();

    for (int s = 1; s < SEQ; ++s) {
        const int tok = inputs[b * SEQ + s];
        x_s[t] = emb[(size_t)tok * EDIM + t];
        __syncthreads();

        float g0 = bias[t];
        float g1 = bias[512 + t];
        float g2 = bias[1024 + t];
        float g3 = bias[1536 + t];
        for (int e = 0; e < EDIM; ++e) {
            const float xv = x_s[e];
            const float hv = h_s[e];
            const float* wxr = Wx + (size_t)e * 2048;
            const float* whr = Wh + (size_t)e * 2048;
            g0 += xv * wxr[t]        + hv * whr[t];
            g1 += xv * wxr[512 + t]  + hv * whr[512 + t];
            g2 += xv * wxr[1024 + t] + hv * whr[1024 + t];
            g3 += xv * wxr[1536 + t] + hv * whr[1536 + t];
        }
        const float nc = sigf(g1) * c_s[t] + sigf(g0) * tanhf(g2);
        const float nh = sigf(g3) * tanhf(nc);
        eos = eos || (x_s[1] != 0.0f);
        __syncthreads();
        c_s[t] = nc;
        h_s[t] = nh;
        __syncthreads();
        if (eos) break;
    }

    out[b * HDIM + t]                = c_s[t];
    out[BATCH * HDIM + b * HDIM + t] = h_s[t];
}

extern "C" void kernel_launch(void* const* d_in, const int* in_sizes, int n_in,
                              void* d_out, int out_size, void* d_ws, size_t ws_size,
                              hipStream_t stream) {
    const int*   inputs = (const int*)  d_in[0];
    const float* emb    = (const float*)d_in[1];
    const float* Wx     = (const float*)d_in[2];
    const float* Wh     = (const float*)d_in[3];
    const float* bias   = (const float*)d_in[4];
    float* out   = (float*)d_out;
    int*   flags = (int*)d_ws;
    float* partials = (float*)((char*)d_ws + WS_PARTIAL_OFF);

    gemm_partial_kernel<<<CTILES * ECHUNKS, 512, 0, stream>>>(inputs, emb, Wx, partials);
    reduce_pointwise_kernel<<<(BATCH * HDIM) / 256, 256, 0, stream>>>(
        inputs, emb, partials, bias, out, flags);
    tail_kernel<<<BATCH, 512, 0, stream>>>(inputs, emb, Wx, Wh, bias, out, flags);
}

// Round 3
// 13.115 us; speedup vs baseline: 2.4149x; 1.1609x over previous
//
#include <hip/hip_runtime.h>

// Masked LSTM encoder. Facts exploited:
//  - h0 = c0 = 0 -> step 0 is gates = x0 @ Wx + b; the f-gate is dead (c0=0),
//    so only i,g,o columns (1536 of 2048) are ever computed.
//  - is_eos[b] |= (embedding[token][EOS_ID=1] != 0): a N(0,0.02) float -> true
//    after step 0 with probability 1, freezing (c,h) at step-0 values.
//  - K1: split-K GEMM partials for x0@Wx, lane=batch (wave-uniform Wx cols ->
//    scalar loads, Wx fetched once globally), LDS-transposed so stores land
//    coalesced in [ec][b][col] layout.
//  - K2: one block per batch owns the WHOLE state vector -> reduce + bias +
//    pointwise + eos flag + faithful sequential tail fused in one kernel
//    (tail exits immediately on this input; no cross-block dependencies).

#define SEQ      512
#define EDIM     512
#define HDIM     512
#define BATCH    64
#define NCOMPACT 1536          // compact cols: i(0..511), g(512..1023), o(1024..1535)
#define ECHUNKS  8             // split-K factor
#define ELEN     (EDIM / ECHUNKS)   // 64
#define CTILES   (NCOMPACT / 64)    // 24

__device__ __forceinline__ float sigf(float x) { return 1.0f / (1.0f + __expf(-x)); }

// ---- K1: partial GEMM, 192 blocks x 512. Block = 64 compact cols x 64-e chunk.
// lane (t&63) = batch; wave (t>>6) = 8 consecutive cols (wave-uniform -> s_load).
__global__ __launch_bounds__(512) void gemm_partial_kernel(
    const int* __restrict__ inputs, const float* __restrict__ emb,
    const float* __restrict__ Wx, float* __restrict__ partials)
{
    const int ct   = blockIdx.x >> 3;      // 0..23  compact col tile
    const int ec   = blockIdx.x & 7;       // 0..7   e-chunk
    const int e0   = ec * ELEN;
    const int t    = threadIdx.x;
    const int lane = t & 63;               // = batch in compute phase
    const int w    = __builtin_amdgcn_readfirstlane(t >> 6);  // wave 0..7
    const int gate = ct >> 3;              // 0:i 1:g 2:o
    const int gofs = (gate == 0) ? 0 : (gate == 1 ? 1024 : 1536);
    const int wcol = gofs + (ct & 7) * 64 + w * 8;  // original Wx col, wave-uniform

    __shared__ float x_s[ELEN][BATCH + 1];  // [e][b]: writes & reads conflict-free
    __shared__ float g_s[64][BATCH + 1];    // [cc_local][b]: transpose buffer

    // Stage x chunk: wave w stages batches w*8..w*8+7; lane sweeps e (coalesced
    // global read; LDS write addr = lane*65+b -> consecutive banks, free).
    #pragma unroll
    for (int k = 0; k < 8; ++k) {
        const int b   = w * 8 + k;
        const int tok = inputs[b * SEQ];
        x_s[lane][b] = emb[(size_t)tok * EDIM + e0 + lane];
    }
    __syncthreads();

    float acc[8] = {};
    #pragma unroll 8
    for (int e = 0; e < ELEN; ++e) {
        const float xv = x_s[e][lane];                    // conflict-free b32
        const float* row = Wx + (size_t)(e0 + e) * 2048 + wcol;  // wave-uniform
        #pragma unroll
        for (int wc = 0; wc < 8; ++wc)
            acc[wc] += xv * row[wc];                      // scalar-loadable Wx
    }

    // Transpose through LDS so global stores are coalesced in [ec][b][cc].
    #pragma unroll
    for (int wc = 0; wc < 8; ++wc)
        g_s[w * 8 + wc][lane] = acc[wc];                  // lanes consecutive: free
    __syncthreads();

    #pragma unroll
    for (int k = 0; k < 8; ++k) {
        const int b = w * 8 + k;
        // read g_s[lane][b]: bank (lane+b)%32 -> 2-way, free. store coalesced.
        partials[((size_t)ec * BATCH + b) * NCOMPACT + ct * 64 + lane] = g_s[lane][b];
    }
}

// ---- K2: one block per batch. Reduce partials + bias + pointwise LSTM,
// recompute eos flag locally, run faithful tail only if not frozen.
__global__ __launch_bounds__(512) void reduce_pointwise_tail_kernel(
    const int* __restrict__ inputs, const float* __restrict__ emb,
    const float* __restrict__ Wx, const float* __restrict__ Wh,
    const float* __restrict__ bias, const float* __restrict__ partials,
    float* __restrict__ out)
{
    const int b = blockIdx.x;
    const int j = threadIdx.x;              // 0..511

    __shared__ float h_s[HDIM];
    __shared__ float c_s[HDIM];
    __shared__ float x_s[EDIM];

    float gi = bias[j];
    float gg = bias[1024 + j];
    float go = bias[1536 + j];
    #pragma unroll
    for (int ec = 0; ec < ECHUNKS; ++ec) {
        const float* p = partials + ((size_t)ec * BATCH + b) * NCOMPACT;
        gi += p[j];                          // coalesced (lanes = j)
        gg += p[512 + j];
        go += p[1024 + j];
    }

    float c = sigf(gi) * tanhf(gg);          // c0 = 0 -> f-gate dead
    float h = sigf(go) * tanhf(c);

    // EOS after step 0 (block-uniform; broadcast loads).
    const int tok0 = inputs[b * SEQ];
    const bool frozen = (emb[(size_t)tok0 * EDIM + 1] != 0.0f);

    if (frozen) {                            // block-uniform branch
        out[b * HDIM + j]                = c;
        out[BATCH * HDIM + b * HDIM + j] = h;
        return;
    }

    // Faithful sequential tail, steps 1..511.
    c_s[j] = c;
    h_s[j] = h;
    bool eos = false;
    __syncthreads();

    const float b0 = bias[j];
    const float b1 = bias[512 + j];
    const float b2 = bias[1024 + j];
    const float b3 = bias[1536 + j];

    for (int s = 1; s < SEQ; ++s) {
        const int tok = inputs[b * SEQ + s];
        x_s[j] = emb[(size_t)tok * EDIM + j];
        __syncthreads();

        float g0 = b0, g1 = b1, g2 = b2, g3 = b3;
        for (int e = 0; e < EDIM; ++e) {
            const float xv = x_s[e];
            const float hv = h_s[e];
            const float* wxr = Wx + (size_t)e * 2048;
            const float* whr = Wh + (size_t)e * 2048;
            g0 += xv * wxr[j]        + hv * whr[j];
            g1 += xv * wxr[512 + j]  + hv * whr[512 + j];
            g2 += xv * wxr[1024 + j] + hv * whr[1024 + j];
            g3 += xv * wxr[1536 + j] + hv * whr[1536 + j];
        }
        const float nc = sigf(g1) * c_s[j] + sigf(g0) * tanhf(g2);
        const float nh = sigf(g3) * tanhf(nc);
        eos = eos || (x_s[1] != 0.0f);       // token s raises flag AFTER update
        __syncthreads();
        c_s[j] = nc;
        h_s[j] = nh;
        __syncthreads();
        if (eos) break;                      // block-uniform
    }

    out[b * HDIM + j]                = c_s[j];
    out[BATCH * HDIM + b * HDIM + j] = h_s[j];
}

extern "C" void kernel_launch(void* const* d_in, const int* in_sizes, int n_in,
                              void* d_out, int out_size, void* d_ws, size_t ws_size,
                              hipStream_t stream) {
    const int*   inputs = (const int*)  d_in[0];
    const float* emb    = (const float*)d_in[1];
    const float* Wx     = (const float*)d_in[2];
    const float* Wh     = (const float*)d_in[3];
    const float* bias   = (const float*)d_in[4];
    float* out      = (float*)d_out;
    float* partials = (float*)d_ws;   // ECHUNKS*BATCH*NCOMPACT floats = 3 MB

    gemm_partial_kernel<<<CTILES * ECHUNKS, 512, 0, stream>>>(inputs, emb, Wx, partials);
    reduce_pointwise_tail_kernel<<<BATCH, 512, 0, stream>>>(
        inputs, emb, Wx, Wh, bias, partials, out);
}